// Round 2
// baseline (3591.866 us; speedup 1.0000x reference)
//
#include <hip/hip_runtime.h>
#include <hip/hip_bf16.h>

// DKVMN forward, restructured (all f32 I/O per harness dtype rules):
//   precompute W[5001,50]  = softmax(q_emb @ key_mem^T)      (per-q table)
//              Q1[5001,50] = q_emb @ pred_w1[200:250] + b1   (per-q table)
//              E[10001,200]= sigmoid(qa_emb @ erase_w + eb)  (per-qa table)
//              A[10001,200]= tanh   (qa_emb @ add_w   + ab)  (per-qa table)
//   main: 1 block per batch element b; Mv[50][200] f32 held in registers
//         (thread v holds column v, 50 VGPRs); w row via uniform scalar loads.
// Workspace requirement: ~18.1 MB.

#define NQ1   5001     // N_Q + 1
#define NQA   10001    // 2*N_Q + 1
#define MEMN  50
#define KD    50
#define VD    200
#define FC    50
#define BB    2048
#define SS    200
#define EA_R  16

__device__ __forceinline__ float fast_sigmoid(float x) { return 1.f / (1.f + __expf(-x)); }
__device__ __forceinline__ float fast_tanh(float x) {
    float e2 = __expf(2.f * x);           // inf-safe: e2=inf -> 1, e2=0 -> -1
    return 1.f - 2.f / (e2 + 1.f);
}

// ---- per-q tables: softmax attention row + q-half of pred MLP layer 1 ----
__global__ void build_wq(const float* __restrict__ qemb,
                         const float* __restrict__ km,
                         const float* __restrict__ w1,
                         const float* __restrict__ b1,
                         float* __restrict__ Wt, float* __restrict__ Q1) {
    const int q = blockIdx.x;
    const int f = threadIdx.x;          // 0..63, one wave
    __shared__ float qrow[KD];
    if (f < KD) qrow[f] = qemb[q * KD + f];
    __syncthreads();

    float s = -1e30f;
    if (f < MEMN) {
        s = 0.f;
        #pragma unroll
        for (int k = 0; k < KD; ++k) s = fmaf(qrow[k], km[f * KD + k], s);
    }
    float mx = s;
    #pragma unroll
    for (int off = 32; off >= 1; off >>= 1) mx = fmaxf(mx, __shfl_xor(mx, off, 64));
    float e = (f < MEMN) ? __expf(s - mx) : 0.f;
    float sum = e;
    #pragma unroll
    for (int off = 32; off >= 1; off >>= 1) sum += __shfl_xor(sum, off, 64);
    if (f < MEMN) Wt[q * MEMN + f] = e / sum;

    if (f < FC) {
        float h = b1[f];
        #pragma unroll
        for (int k = 0; k < KD; ++k)
            h = fmaf(qrow[k], w1[(VD + k) * FC + f], h);
        Q1[q * FC + f] = h;
    }
}

// ---- per-qa tables: erase (sigmoid) and add (tanh) rows ----
__global__ void build_ea(const float* __restrict__ qaemb,
                         const float* __restrict__ ew,
                         const float* __restrict__ ebias,
                         const float* __restrict__ aw,
                         const float* __restrict__ abias,
                         float* __restrict__ E, float* __restrict__ A) {
    __shared__ float qT[VD][EA_R];      // [k][r], 12.8 KB
    const int tid = threadIdx.x;
    const int r0 = blockIdx.x * EA_R;
    if (tid < VD) {
        #pragma unroll
        for (int r = 0; r < EA_R; ++r) {
            int row = r0 + r;
            qT[tid][r] = (row < NQA) ? qaemb[(size_t)row * VD + tid] : 0.f;
        }
    }
    __syncthreads();
    if (tid >= VD) return;

    float accE[EA_R], accA[EA_R];
    #pragma unroll
    for (int r = 0; r < EA_R; ++r) { accE[r] = 0.f; accA[r] = 0.f; }
    for (int k = 0; k < VD; ++k) {
        float we = ew[k * VD + tid];
        float wa = aw[k * VD + tid];
        #pragma unroll
        for (int r = 0; r < EA_R; ++r) {
            float qv = qT[k][r];
            accE[r] = fmaf(qv, we, accE[r]);
            accA[r] = fmaf(qv, wa, accA[r]);
        }
    }
    float be = ebias[tid], ba = abias[tid];
    #pragma unroll
    for (int r = 0; r < EA_R; ++r) {
        int row = r0 + r;
        if (row < NQA) {
            E[(size_t)row * VD + tid] = fast_sigmoid(accE[r] + be);
            A[(size_t)row * VD + tid] = fast_tanh(accA[r] + ba);
        }
    }
}

// ---- main recurrent kernel: one block per batch element ----
__global__ void dkvmn_main(const int* __restrict__ qd, const int* __restrict__ qad,
                           const float* __restrict__ Wtab, const float* __restrict__ Q1tab,
                           const float* __restrict__ Etab, const float* __restrict__ Atab,
                           const float* __restrict__ ivm,
                           const float* __restrict__ w1,
                           const float* __restrict__ w2,
                           const float* __restrict__ b2,
                           float* __restrict__ out) {
    const int tid  = threadIdx.x;
    const int b    = blockIdx.x;
    const int v    = tid;               // value-dim column, active if v < VD
    const int lane = tid & 63;
    const int wv   = tid >> 6;          // wave id 0..3

    __shared__ alignas(16) float read_lds[4 * 52];   // 50-chunks padded to 52 (16B-aligned)
    __shared__ alignas(16) float part_lds[4 * 52];

    // Mv column in registers
    float mv[MEMN];
    if (v < VD) {
        #pragma unroll
        for (int m = 0; m < MEMN; ++m) mv[m] = ivm[m * VD + v];
    }
    // W1r fragment: thread (f=lane, j=wv) holds pred_w1[wv*50+i][f], i=0..49
    float w1r[50];
    if (lane < FC) {
        #pragma unroll
        for (int i = 0; i < 50; ++i) w1r[i] = w1[(wv * 50 + i) * FC + lane];
    } else {
        #pragma unroll
        for (int i = 0; i < 50; ++i) w1r[i] = 0.f;
    }
    const float w2f = (tid < FC) ? w2[tid] : 0.f;
    const float b2f = b2[0];

    const int* qrow_i  = qd  + b * SS;
    const int* qarow_i = qad + b * SS;

    // precompute this thread's read_lds write slot
    const int jchunk = v / 50;
    const int wslot  = jchunk * 52 + (v - jchunk * 50);

    for (int t = 0; t < SS; ++t) {
        const int q  = __builtin_amdgcn_readfirstlane(qrow_i[t]);
        const int qa = __builtin_amdgcn_readfirstlane(qarow_i[t]);
        const float* wrow = Wtab + q * MEMN;   // uniform -> s_load

        float ev = 0.f, av = 0.f;
        if (v < VD) {
            ev = Etab[(size_t)qa * VD + v];
            av = Atab[(size_t)qa * VD + v];
        }

        if (v < VD) {
            float rd0 = 0.f, rd1 = 0.f;
            #pragma unroll
            for (int m = 0; m < MEMN; m += 2) {
                float wm0 = wrow[m];
                float wm1 = wrow[m + 1];
                rd0 = fmaf(wm0, mv[m], rd0);
                float u0 = fmaf(-ev, mv[m], av);        // a - e*mv
                mv[m] = fmaf(wm0, u0, mv[m]);           // mv + w*(a - e*mv)
                rd1 = fmaf(wm1, mv[m + 1], rd1);
                float u1 = fmaf(-ev, mv[m + 1], av);
                mv[m + 1] = fmaf(wm1, u1, mv[m + 1]);
            }
            read_lds[wslot] = rd0 + rd1;
        }
        __syncthreads();

        // per-wave partial of read @ W1r over this wave's 50-chunk
        float part = 0.f;
        {
            const float* rl = read_lds + wv * 52;
            #pragma unroll
            for (int i = 0; i < 48; i += 4) {
                float4 x = *(const float4*)(rl + i);     // broadcast b128
                part = fmaf(x.x, w1r[i],     part);
                part = fmaf(x.y, w1r[i + 1], part);
                part = fmaf(x.z, w1r[i + 2], part);
                part = fmaf(x.w, w1r[i + 3], part);
            }
            part = fmaf(rl[48], w1r[48], part);
            part = fmaf(rl[49], w1r[49], part);
        }
        if (lane < FC) part_lds[wv * 52 + lane] = part;
        __syncthreads();

        // wave 0 finishes: h = tanh(sum + q1), p = sigmoid(h @ w2 + b2)
        if (wv == 0) {
            float pf = 0.f;
            if (lane < FC) {
                float h = part_lds[lane] + part_lds[52 + lane] +
                          part_lds[104 + lane] + part_lds[156 + lane] +
                          Q1tab[q * FC + lane];
                pf = fast_tanh(h) * w2f;
            }
            #pragma unroll
            for (int off = 32; off >= 1; off >>= 1) pf += __shfl_xor(pf, off, 64);
            if (lane == 0)
                out[b * SS + t] = fast_sigmoid(pf + b2f);
        }
        // barrier accounting: read_lds written in (sync2(t), sync1(t+1)),
        // read in (sync1, sync2); part_lds written in (sync1, sync2), read
        // by wave0 before it reaches sync1(t+1) -> no third barrier needed.
    }
}

extern "C" void kernel_launch(void* const* d_in, const int* in_sizes, int n_in,
                              void* d_out, int out_size, void* d_ws, size_t ws_size,
                              hipStream_t stream) {
    const int* qd  = (const int*)d_in[0];
    const int* qad = (const int*)d_in[1];
    const float* qemb  = (const float*)d_in[2];
    const float* qaemb = (const float*)d_in[3];
    const float* km    = (const float*)d_in[4];
    const float* ivm   = (const float*)d_in[5];
    const float* ew    = (const float*)d_in[6];
    const float* eb    = (const float*)d_in[7];
    const float* aw    = (const float*)d_in[8];
    const float* ab    = (const float*)d_in[9];
    const float* w1    = (const float*)d_in[10];
    const float* b1    = (const float*)d_in[11];
    const float* w2    = (const float*)d_in[12];
    const float* b2    = (const float*)d_in[13];
    float* out = (float*)d_out;

    // workspace layout (256B-aligned chunks), total ~18.1 MB
    char* ws = (char*)d_ws;
    float* Wt = (float*)(ws);                         // 5001*50*4  = 1,000,200
    float* Q1 = (float*)(ws + 1000448);               // 5001*50*4
    float* E  = (float*)(ws + 2000896);               // 10001*200*4 = 8,000,800
    float* A  = (float*)(ws + 2000896 + 8001024);
    (void)ws_size; (void)in_sizes; (void)n_in; (void)out_size;

    // outputs 1..3 are zeros (f32)
    hipMemsetAsync(out + (size_t)BB * SS, 0, (size_t)3 * BB * SS * sizeof(float), stream);

    build_wq<<<NQ1, 64, 0, stream>>>(qemb, km, w1, b1, Wt, Q1);
    build_ea<<<(NQA + EA_R - 1) / EA_R, 256, 0, stream>>>(qaemb, ew, eb, aw, ab, E, A);
    dkvmn_main<<<BB, 256, 0, stream>>>(qd, qad, Wt, Q1, E, A, ivm, w1, w2, b2, out);
}

// Round 3
// 704.433 us; speedup vs baseline: 5.0989x; 5.0989x over previous
//
#include <hip/hip_runtime.h>

// DKVMN forward, v3 — decouple prediction MLP from the recurrence.
//  k1 build_wq : W[5001,50]=softmax(q_emb@K^T), Q1[5001,50]=q_emb@W1[200:250]+b1
//  k2 build_ea : EA[10001,200] packed bf16 {e=sigmoid(...), a=tanh(...)}
//  k3 dkvmn_state: BARRIER-FREE recurrence. 64-thread blocks, 4 blocks per batch
//     element (column chunks). mv[50] in regs; wrow via uniform s_load; EA
//     prefetched one step ahead; writes read[b,t,v] as bf16.
//  k4 mlp_pred : p = sigmoid(w2 . tanh(read@W1a + Q1[q]) + b2), 16 rows/block,
//     W1a fragments in regs (wave w owns k-chunk [w*52, w*52+52)).
// Workspace: Wt 1MB | Q1 1MB | EA 8MB | READ 164MB  (~174MB total).

#define NQ1   5001
#define NQA   10001
#define MEMN  50
#define KD    50
#define VD    200
#define FC    50
#define BB    2048
#define SS    200
#define EA_R  16

typedef unsigned int   u32;
typedef unsigned short u16;

__device__ __forceinline__ float fast_sigmoid(float x) { return 1.f / (1.f + __expf(-x)); }
__device__ __forceinline__ float fast_tanh(float x) {
    float e2 = __expf(2.f * x);           // inf-safe
    return 1.f - 2.f / (e2 + 1.f);
}
__device__ __forceinline__ float bfu16_to_f(u16 u) {
    union { float f; u32 i; } x; x.i = ((u32)u) << 16; return x.f;
}
__device__ __forceinline__ u16 f_to_bfu16(float f) {   // RNE, finite inputs only
    union { float f; u32 i; } x; x.f = f;
    return (u16)((x.i + 0x7fffu + ((x.i >> 16) & 1u)) >> 16);
}

// ---- per-q tables ----
__global__ void build_wq(const float* __restrict__ qemb,
                         const float* __restrict__ km,
                         const float* __restrict__ w1,
                         const float* __restrict__ b1,
                         float* __restrict__ Wt, float* __restrict__ Q1) {
    const int q = blockIdx.x;
    const int f = threadIdx.x;          // one wave
    __shared__ float qrow[KD];
    if (f < KD) qrow[f] = qemb[q * KD + f];
    __syncthreads();

    float s = -1e30f;
    if (f < MEMN) {
        s = 0.f;
        #pragma unroll
        for (int k = 0; k < KD; ++k) s = fmaf(qrow[k], km[f * KD + k], s);
    }
    float mx = s;
    #pragma unroll
    for (int off = 32; off >= 1; off >>= 1) mx = fmaxf(mx, __shfl_xor(mx, off, 64));
    float e = (f < MEMN) ? __expf(s - mx) : 0.f;
    float sum = e;
    #pragma unroll
    for (int off = 32; off >= 1; off >>= 1) sum += __shfl_xor(sum, off, 64);
    if (f < MEMN) Wt[q * MEMN + f] = e / sum;

    if (f < FC) {
        float h = b1[f];
        #pragma unroll
        for (int k = 0; k < KD; ++k)
            h = fmaf(qrow[k], w1[(VD + k) * FC + f], h);
        Q1[q * FC + f] = h;
    }
}

// ---- per-qa table, packed {e,a} bf16 ----
__global__ void build_ea(const float* __restrict__ qaemb,
                         const float* __restrict__ ew,
                         const float* __restrict__ ebias,
                         const float* __restrict__ aw,
                         const float* __restrict__ abias,
                         u32* __restrict__ EA) {
    __shared__ float qT[VD][EA_R];
    const int tid = threadIdx.x;
    const int r0 = blockIdx.x * EA_R;
    if (tid < VD) {
        #pragma unroll
        for (int r = 0; r < EA_R; ++r) {
            int row = r0 + r;
            qT[tid][r] = (row < NQA) ? qaemb[(size_t)row * VD + tid] : 0.f;
        }
    }
    __syncthreads();
    if (tid >= VD) return;

    float accE[EA_R], accA[EA_R];
    #pragma unroll
    for (int r = 0; r < EA_R; ++r) { accE[r] = 0.f; accA[r] = 0.f; }
    for (int k = 0; k < VD; ++k) {
        float we = ew[k * VD + tid];
        float wa = aw[k * VD + tid];
        #pragma unroll
        for (int r = 0; r < EA_R; ++r) {
            float qv = qT[k][r];
            accE[r] = fmaf(qv, we, accE[r]);
            accA[r] = fmaf(qv, wa, accA[r]);
        }
    }
    float be = ebias[tid], ba = abias[tid];
    #pragma unroll
    for (int r = 0; r < EA_R; ++r) {
        int row = r0 + r;
        if (row < NQA) {
            u16 eb16 = f_to_bfu16(fast_sigmoid(accE[r] + be));
            u16 ab16 = f_to_bfu16(fast_tanh(accA[r] + ba));
            EA[(size_t)row * VD + tid] = (u32)eb16 | ((u32)ab16 << 16);
        }
    }
}

// ---- barrier-free recurrent kernel: 1 wave = 64 columns of one batch elem ----
__global__ __launch_bounds__(64) void dkvmn_state(
        const int* __restrict__ qd, const int* __restrict__ qad,
        const float* __restrict__ Wtab, const u32* __restrict__ EA,
        const float* __restrict__ ivm, u16* __restrict__ READ) {
    const int lane  = threadIdx.x;
    const int bid   = blockIdx.x;
    const int b     = bid >> 2;
    const int chunk = bid & 3;
    const int v     = chunk * 64 + lane;         // 0..255
    const bool active = v < VD;
    const int vc = active ? v : VD - 1;

    float mv[MEMN];
    #pragma unroll
    for (int m = 0; m < MEMN; ++m) mv[m] = ivm[m * VD + vc];

    const int base = b * SS;
    int q = __builtin_amdgcn_readfirstlane(qd[base]);
    {   // software pipeline: ea holds step-t values
    }
    u32 ea = EA[(size_t)qad[base] * VD + vc];

    for (int t = 0; t < SS; ++t) {
        // prefetch step t+1 (covers E/A gather latency with this step's compute)
        int q_n = 0, qa_n = 0;
        if (t + 1 < SS) {
            q_n  = __builtin_amdgcn_readfirstlane(qd[base + t + 1]);
            qa_n = qad[base + t + 1];
        }
        u32 ea_n = EA[(size_t)qa_n * VD + vc];

        const float* wrow = Wtab + q * MEMN;     // uniform -> s_load
        float ev = bfu16_to_f((u16)(ea & 0xffffu));
        float av = bfu16_to_f((u16)(ea >> 16));

        float rd0 = 0.f, rd1 = 0.f;
        #pragma unroll
        for (int m = 0; m < MEMN; m += 2) {
            float wm0 = wrow[m], wm1 = wrow[m + 1];
            rd0 = fmaf(wm0, mv[m], rd0);
            mv[m] = fmaf(wm0, fmaf(-ev, mv[m], av), mv[m]);
            rd1 = fmaf(wm1, mv[m + 1], rd1);
            mv[m + 1] = fmaf(wm1, fmaf(-ev, mv[m + 1], av), mv[m + 1]);
        }
        if (active) READ[(size_t)(base + t) * VD + v] = f_to_bfu16(rd0 + rd1);
        q = q_n; ea = ea_n;
    }
}

// ---- prediction MLP over all B*S rows: 16 rows per 256-thread block ----
// wave w owns k-chunk [w*52, w*52+52) (52*4=208-float padded rows, 16B aligned)
__global__ __launch_bounds__(256) void mlp_pred(
        const u16* __restrict__ RD, const int* __restrict__ qd,
        const float* __restrict__ Q1tab, const float* __restrict__ w1,
        const float* __restrict__ w2, const float* __restrict__ b2,
        float* __restrict__ out) {
    const int tid = threadIdx.x, lane = tid & 63, wv = tid >> 6;
    __shared__ alignas(16) float rl[16][208];
    __shared__ float parts[16][4][52];

    float w1r[52];
    #pragma unroll
    for (int i = 0; i < 52; ++i) {
        int gk = wv * 52 + i;
        w1r[i] = (gk < VD && lane < FC) ? w1[gk * FC + lane] : 0.f;
    }
    const float w2f = (lane < FC) ? w2[lane] : 0.f;
    const float b2f = b2[0];

    const int row0 = blockIdx.x * 16;
    const u32* RDu = (const u32*)RD;
    for (int idx = tid; idx < 1600; idx += 256) {       // 16 rows * 100 u32
        int r = idx / 100, k2 = idx - r * 100;
        u32 pr = RDu[(size_t)(row0 + r) * 100 + k2];
        rl[r][2 * k2]     = bfu16_to_f((u16)(pr & 0xffffu));
        rl[r][2 * k2 + 1] = bfu16_to_f((u16)(pr >> 16));
    }
    if (tid < 128) rl[tid >> 3][200 + (tid & 7)] = 0.f; // zero the pad
    __syncthreads();

    #pragma unroll 4
    for (int j = 0; j < 16; ++j) {
        const float* rlj = &rl[j][wv * 52];
        float part = 0.f;
        #pragma unroll
        for (int i = 0; i < 52; i += 4) {
            float4 x = *(const float4*)(rlj + i);       // broadcast b128
            part = fmaf(x.x, w1r[i],     part);
            part = fmaf(x.y, w1r[i + 1], part);
            part = fmaf(x.z, w1r[i + 2], part);
            part = fmaf(x.w, w1r[i + 3], part);
        }
        if (lane < FC) parts[j][wv][lane] = part;
    }
    __syncthreads();

    #pragma unroll
    for (int jj = 0; jj < 4; ++jj) {
        int j = wv * 4 + jj;
        int row = row0 + j;
        float pf = 0.f;
        if (lane < FC) {
            float h = parts[j][0][lane] + parts[j][1][lane] +
                      parts[j][2][lane] + parts[j][3][lane] +
                      Q1tab[qd[row] * FC + lane];
            pf = fast_tanh(h) * w2f;
        }
        #pragma unroll
        for (int off = 32; off >= 1; off >>= 1) pf += __shfl_xor(pf, off, 64);
        if (lane == 0) out[row] = fast_sigmoid(pf + b2f);
    }
}

// ---- fallback (barrier version) if workspace is too small for READ ----
__global__ void dkvmn_main(const int* __restrict__ qd, const int* __restrict__ qad,
                           const float* __restrict__ Wtab, const float* __restrict__ Q1tab,
                           const u32* __restrict__ EA,
                           const float* __restrict__ ivm,
                           const float* __restrict__ w1,
                           const float* __restrict__ w2,
                           const float* __restrict__ b2,
                           float* __restrict__ out) {
    const int tid  = threadIdx.x;
    const int b    = blockIdx.x;
    const int v    = tid;
    const int lane = tid & 63;
    const int wv   = tid >> 6;

    __shared__ alignas(16) float read_lds[4 * 52];
    __shared__ alignas(16) float part_lds[4 * 52];

    float mv[MEMN];
    if (v < VD) {
        #pragma unroll
        for (int m = 0; m < MEMN; ++m) mv[m] = ivm[m * VD + v];
    }
    float w1r[50];
    if (lane < FC) {
        #pragma unroll
        for (int i = 0; i < 50; ++i) w1r[i] = w1[(wv * 50 + i) * FC + lane];
    } else {
        #pragma unroll
        for (int i = 0; i < 50; ++i) w1r[i] = 0.f;
    }
    const float w2f = (tid < FC) ? w2[tid] : 0.f;
    const float b2f = b2[0];

    const int* qrow_i  = qd  + b * SS;
    const int* qarow_i = qad + b * SS;
    const int jchunk = v / 50;
    const int wslot  = jchunk * 52 + (v - jchunk * 50);

    for (int t = 0; t < SS; ++t) {
        const int q  = __builtin_amdgcn_readfirstlane(qrow_i[t]);
        const int qa = __builtin_amdgcn_readfirstlane(qarow_i[t]);
        const float* wrow = Wtab + q * MEMN;

        u32 ea = 0;
        if (v < VD) ea = EA[(size_t)qa * VD + v];
        float ev = bfu16_to_f((u16)(ea & 0xffffu));
        float av = bfu16_to_f((u16)(ea >> 16));

        if (v < VD) {
            float rd0 = 0.f, rd1 = 0.f;
            #pragma unroll
            for (int m = 0; m < MEMN; m += 2) {
                float wm0 = wrow[m], wm1 = wrow[m + 1];
                rd0 = fmaf(wm0, mv[m], rd0);
                mv[m] = fmaf(wm0, fmaf(-ev, mv[m], av), mv[m]);
                rd1 = fmaf(wm1, mv[m + 1], rd1);
                mv[m + 1] = fmaf(wm1, fmaf(-ev, mv[m + 1], av), mv[m + 1]);
            }
            read_lds[wslot] = rd0 + rd1;
        }
        __syncthreads();

        float part = 0.f;
        {
            const float* rlc = read_lds + wv * 52;
            #pragma unroll
            for (int i = 0; i < 48; i += 4) {
                float4 x = *(const float4*)(rlc + i);
                part = fmaf(x.x, w1r[i],     part);
                part = fmaf(x.y, w1r[i + 1], part);
                part = fmaf(x.z, w1r[i + 2], part);
                part = fmaf(x.w, w1r[i + 3], part);
            }
            part = fmaf(rlc[48], w1r[48], part);
            part = fmaf(rlc[49], w1r[49], part);
        }
        if (lane < FC) part_lds[wv * 52 + lane] = part;
        __syncthreads();

        if (wv == 0) {
            float pf = 0.f;
            if (lane < FC) {
                float h = part_lds[lane] + part_lds[52 + lane] +
                          part_lds[104 + lane] + part_lds[156 + lane] +
                          Q1tab[q * FC + lane];
                pf = fast_tanh(h) * w2f;
            }
            #pragma unroll
            for (int off = 32; off >= 1; off >>= 1) pf += __shfl_xor(pf, off, 64);
            if (lane == 0) out[b * SS + t] = fast_sigmoid(pf + b2f);
        }
    }
}

extern "C" void kernel_launch(void* const* d_in, const int* in_sizes, int n_in,
                              void* d_out, int out_size, void* d_ws, size_t ws_size,
                              hipStream_t stream) {
    const int* qd  = (const int*)d_in[0];
    const int* qad = (const int*)d_in[1];
    const float* qemb  = (const float*)d_in[2];
    const float* qaemb = (const float*)d_in[3];
    const float* km    = (const float*)d_in[4];
    const float* ivm   = (const float*)d_in[5];
    const float* ew    = (const float*)d_in[6];
    const float* eb    = (const float*)d_in[7];
    const float* aw    = (const float*)d_in[8];
    const float* ab    = (const float*)d_in[9];
    const float* w1    = (const float*)d_in[10];
    const float* b1    = (const float*)d_in[11];
    const float* w2    = (const float*)d_in[12];
    const float* b2    = (const float*)d_in[13];
    float* out = (float*)d_out;
    (void)in_sizes; (void)n_in; (void)out_size;

    char* ws = (char*)d_ws;
    float* Wt = (float*)(ws);                      // 1,000,200 -> pad 1,000,448
    float* Q1 = (float*)(ws + 1000448);            // 1,000,200 -> pad 1,000,448
    u32*   EA = (u32*)  (ws + 2000896);            // 8,000,800 -> pad 8,001,024
    u16*   RD = (u16*)  (ws + 2000896 + 8001024);  // 163,840,000
    const size_t need = 10001920ull + (size_t)BB * SS * VD * 2ull;

    hipMemsetAsync(out + (size_t)BB * SS, 0, (size_t)3 * BB * SS * sizeof(float), stream);

    build_wq<<<NQ1, 64, 0, stream>>>(qemb, km, w1, b1, Wt, Q1);
    build_ea<<<(NQA + EA_R - 1) / EA_R, 256, 0, stream>>>(qaemb, ew, eb, aw, ab, EA);

    if (ws_size >= need) {
        dkvmn_state<<<BB * 4, 64, 0, stream>>>(qd, qad, Wt, EA, ivm, RD);
        mlp_pred<<<(BB * SS) / 16, 256, 0, stream>>>(RD, qd, Q1, w1, w2, b2, out);
    } else {
        dkvmn_main<<<BB, 256, 0, stream>>>(qd, qad, Wt, Q1, EA, ivm, w1, w2, b2, out);
    }
}

// Round 6
// 499.389 us; speedup vs baseline: 7.1925x; 1.4106x over previous
//
#include <hip/hip_runtime.h>

// DKVMN forward, v6.
//  R5 isolation: state(pk)+mlp(f32) failed at the BIT-IDENTICAL absmax as
//  R4 state(pk)+mlp(MFMA) -> bug is in the pk state kernel; MFMA mlp is good.
//  Bug found: MEMN/2=25 is ODD; loop `i<25,i+=2` touching mv[i],mv[i+1] read
//  mv[25] OOB (garbage) + wrow[50..51] (next q's row). Fixed with 12 pair
//  iterations + explicit tail for mv[24].
//  k1 build_wq : W[5001,50]=softmax(q_emb@K^T), Q1[5001,50]=q_emb@W1[200:250]+b1
//  k2 build_ea : EA[10001,200] packed bf16 {e,a}
//  k2b pack_w1 : W1 -> bf16 MFMA B-frag order [4 nt][7 kt][64 lane][8]
//  k3 dkvmn_state: barrier-free recurrence, 256-thr blocks, v_pk_fma_f32,
//      EA prefetch depth 2, writes RD bf16.
//  k4 mlp_pred : MFMA 16x16x32 bf16 GEMM [B*S,224]@[224,64] + fused epilogue.
// Workspace: Wt 1MB | Q1 1MB | EA 8MB | W1s 32KB | RD 164MB (~174MB total).

#define NQ1   5001
#define NQA   10001
#define MEMN  50
#define KD    50
#define VD    200
#define FC    50
#define BB    2048
#define SS    200
#define EA_R  16

typedef unsigned int   u32;
typedef unsigned short u16;
typedef float  v2f  __attribute__((ext_vector_type(2)));
typedef short  s8v  __attribute__((ext_vector_type(8)));   // 8 bf16 (4 VGPRs)
typedef float  f4v  __attribute__((ext_vector_type(4)));   // MFMA C/D

__device__ __forceinline__ float fast_sigmoid(float x) { return 1.f / (1.f + __expf(-x)); }
__device__ __forceinline__ float fast_tanh(float x) {
    float e2 = __expf(2.f * x);           // inf-safe
    return 1.f - 2.f / (e2 + 1.f);
}
__device__ __forceinline__ float bfu16_to_f(u16 u) {
    union { float f; u32 i; } x; x.i = ((u32)u) << 16; return x.f;
}
__device__ __forceinline__ u16 f_to_bfu16(float f) {   // RNE, finite inputs
    union { float f; u32 i; } x; x.f = f;
    return (u16)((x.i + 0x7fffu + ((x.i >> 16) & 1u)) >> 16);
}

// ---- per-q tables ----
__global__ void build_wq(const float* __restrict__ qemb,
                         const float* __restrict__ km,
                         const float* __restrict__ w1,
                         const float* __restrict__ b1,
                         float* __restrict__ Wt, float* __restrict__ Q1) {
    const int q = blockIdx.x;
    const int f = threadIdx.x;          // one wave
    __shared__ float qrow[KD];
    if (f < KD) qrow[f] = qemb[q * KD + f];
    __syncthreads();

    float s = -1e30f;
    if (f < MEMN) {
        s = 0.f;
        #pragma unroll
        for (int k = 0; k < KD; ++k) s = fmaf(qrow[k], km[f * KD + k], s);
    }
    float mx = s;
    #pragma unroll
    for (int off = 32; off >= 1; off >>= 1) mx = fmaxf(mx, __shfl_xor(mx, off, 64));
    float e = (f < MEMN) ? __expf(s - mx) : 0.f;
    float sum = e;
    #pragma unroll
    for (int off = 32; off >= 1; off >>= 1) sum += __shfl_xor(sum, off, 64);
    if (f < MEMN) Wt[q * MEMN + f] = e / sum;

    if (f < FC) {
        float h = b1[f];
        #pragma unroll
        for (int k = 0; k < KD; ++k)
            h = fmaf(qrow[k], w1[(VD + k) * FC + f], h);
        Q1[q * FC + f] = h;
    }
}

// ---- per-qa table, packed {e,a} bf16 ----
__global__ void build_ea(const float* __restrict__ qaemb,
                         const float* __restrict__ ew,
                         const float* __restrict__ ebias,
                         const float* __restrict__ aw,
                         const float* __restrict__ abias,
                         u32* __restrict__ EA) {
    __shared__ float qT[VD][EA_R];
    const int tid = threadIdx.x;
    const int r0 = blockIdx.x * EA_R;
    if (tid < VD) {
        #pragma unroll
        for (int r = 0; r < EA_R; ++r) {
            int row = r0 + r;
            qT[tid][r] = (row < NQA) ? qaemb[(size_t)row * VD + tid] : 0.f;
        }
    }
    __syncthreads();
    if (tid >= VD) return;

    float accE[EA_R], accA[EA_R];
    #pragma unroll
    for (int r = 0; r < EA_R; ++r) { accE[r] = 0.f; accA[r] = 0.f; }
    for (int k = 0; k < VD; ++k) {
        float we = ew[k * VD + tid];
        float wa = aw[k * VD + tid];
        #pragma unroll
        for (int r = 0; r < EA_R; ++r) {
            float qv = qT[k][r];
            accE[r] = fmaf(qv, we, accE[r]);
            accA[r] = fmaf(qv, wa, accA[r]);
        }
    }
    float be = ebias[tid], ba = abias[tid];
    #pragma unroll
    for (int r = 0; r < EA_R; ++r) {
        int row = r0 + r;
        if (row < NQA) {
            u16 eb16 = f_to_bfu16(fast_sigmoid(accE[r] + be));
            u16 ab16 = f_to_bfu16(fast_tanh(accA[r] + ba));
            EA[(size_t)row * VD + tid] = (u32)eb16 | ((u32)ab16 << 16);
        }
    }
}

// ---- W1 -> bf16 MFMA B-fragment order: idx = ((nt*7+kt)*64+lane)*8+j,
//      element = w1[k = kt*32+(lane>>4)*8+j][n = nt*16+(lane&15)], 0-padded ----
__global__ void pack_w1(const float* __restrict__ w1, u16* __restrict__ W1s) {
    for (int idx = threadIdx.x; idx < 4 * 7 * 64 * 8; idx += blockDim.x) {
        int j    = idx & 7;
        int lane = (idx >> 3) & 63;
        int kt   = (idx >> 9) % 7;
        int nt   = idx / 3584;
        int k = kt * 32 + ((lane >> 4) << 3) + j;
        int n = nt * 16 + (lane & 15);
        float v = (k < VD && n < FC) ? w1[k * FC + n] : 0.f;
        W1s[idx] = f_to_bfu16(v);
    }
}

// ---- barrier-free recurrence: block=256 (4 indep waves), packed f32 math ----
__global__ __launch_bounds__(256) void dkvmn_state(
        const int* __restrict__ qd, const int* __restrict__ qad,
        const float* __restrict__ Wtab, const u32* __restrict__ EA,
        const float* __restrict__ ivm, u16* __restrict__ READ) {
    const int tid   = threadIdx.x;
    const int lane  = tid & 63;
    const int chunk = tid >> 6;
    const int b     = blockIdx.x;
    const int v     = chunk * 64 + lane;         // 0..255
    const bool active = v < VD;
    const int vc = active ? v : VD - 1;

    v2f mv[25];                                   // 25 v2f = slots 0..49
    #pragma unroll
    for (int i = 0; i < 25; ++i) {
        mv[i].x = ivm[(2 * i) * VD + vc];
        mv[i].y = ivm[(2 * i + 1) * VD + vc];
    }

    const int base = b * SS;
    // software pipeline depth 2 on the EA gather + q indices
    int q_c = __builtin_amdgcn_readfirstlane(qd[base]);
    int q_n = __builtin_amdgcn_readfirstlane(qd[base + 1]);
    int qa0 = __builtin_amdgcn_readfirstlane(qad[base]);
    int qa1 = __builtin_amdgcn_readfirstlane(qad[base + 1]);
    u32 ea_c = EA[(size_t)qa0 * VD + vc];
    u32 ea_n = EA[(size_t)qa1 * VD + vc];

    for (int t = 0; t < SS; ++t) {
        int q_nn = 0, qa_nn = 0;
        if (t + 2 < SS) {
            q_nn  = __builtin_amdgcn_readfirstlane(qd[base + t + 2]);
            qa_nn = __builtin_amdgcn_readfirstlane(qad[base + t + 2]);
        }
        u32 ea_nn = EA[(size_t)qa_nn * VD + vc];

        const float* wrow = Wtab + q_c * MEMN;   // uniform -> s_load
        float ev = bfu16_to_f((u16)(ea_c & 0xffffu));
        float av = bfu16_to_f((u16)(ea_c >> 16));
        v2f nev = { -ev, -ev };
        v2f av2 = {  av,  av };

        v2f rd0 = { 0.f, 0.f }, rd1 = { 0.f, 0.f };
        #pragma unroll
        for (int i = 0; i < 24; i += 2) {        // 12 iters: mv[0..23], slots 0..47
            v2f wm0 = { wrow[2 * i],     wrow[2 * i + 1] };
            v2f wm1 = { wrow[2 * i + 2], wrow[2 * i + 3] };
            rd0 = __builtin_elementwise_fma(wm0, mv[i], rd0);
            mv[i] = __builtin_elementwise_fma(
                wm0, __builtin_elementwise_fma(nev, mv[i], av2), mv[i]);
            rd1 = __builtin_elementwise_fma(wm1, mv[i + 1], rd1);
            mv[i + 1] = __builtin_elementwise_fma(
                wm1, __builtin_elementwise_fma(nev, mv[i + 1], av2), mv[i + 1]);
        }
        {   // tail: mv[24] = slots 48,49
            v2f wmT = { wrow[48], wrow[49] };
            rd0 = __builtin_elementwise_fma(wmT, mv[24], rd0);
            mv[24] = __builtin_elementwise_fma(
                wmT, __builtin_elementwise_fma(nev, mv[24], av2), mv[24]);
        }
        if (active)
            READ[(size_t)(base + t) * VD + v] =
                f_to_bfu16((rd0.x + rd0.y) + (rd1.x + rd1.y));
        q_c = q_n; q_n = q_nn; ea_c = ea_n; ea_n = ea_nn;
    }
}

// ---- prediction MLP via MFMA: per wave one 16-row strip, K=224, N=64 ----
__global__ __launch_bounds__(256) void mlp_pred(
        const u16* __restrict__ RD, const int* __restrict__ qd,
        const float* __restrict__ Q1tab, const u16* __restrict__ W1s,
        const float* __restrict__ w2, const float* __restrict__ b2,
        float* __restrict__ out) {
    const int tid  = threadIdx.x;
    const int lane = tid & 63;
    const int wv   = tid >> 6;
    const int strip = blockIdx.x * 4 + wv;
    const int row0  = strip * 16;

    const int mrow = lane & 15;        // A row within strip / C-D col (feature)
    const int quad = lane >> 4;

    // A fragments: 7 k-tiles, each lane 8 contiguous bf16 of its row
    s8v a[7];
    {
        const u16* arow = RD + (size_t)(row0 + mrow) * VD + quad * 8;
        #pragma unroll
        for (int kt = 0; kt < 7; ++kt)
            a[kt] = *(const s8v*)(arow + kt * 32);   // k>=200 garbage * B=0
    }

    const float b2f = b2[0];
    float pf[4] = {0.f, 0.f, 0.f, 0.f};

    #pragma unroll
    for (int nt = 0; nt < 4; ++nt) {
        s8v bfr[7];
        #pragma unroll
        for (int kt = 0; kt < 7; ++kt)
            bfr[kt] = *(const s8v*)(W1s + (((nt * 7 + kt) * 64) + lane) * 8);

        f4v acc = {0.f, 0.f, 0.f, 0.f};
        #pragma unroll
        for (int kt = 0; kt < 7; ++kt)
            acc = __builtin_amdgcn_mfma_f32_16x16x32_bf16(a[kt], bfr[kt], acc, 0, 0, 0);

        const int f = nt * 16 + mrow;                  // output feature col
        const float w2f = (f < FC) ? w2[f] : 0.f;
        #pragma unroll
        for (int r = 0; r < 4; ++r) {
            int row = row0 + quad * 4 + r;
            float h = acc[r] + Q1tab[qd[row] * FC + f];
            pf[r] = fmaf(fast_tanh(h), w2f, pf[r]);
        }
    }

    // reduce over the 16 lanes holding different f for the same rows
    #pragma unroll
    for (int r = 0; r < 4; ++r) {
        float s = pf[r];
        s += __shfl_xor(s, 1, 64);
        s += __shfl_xor(s, 2, 64);
        s += __shfl_xor(s, 4, 64);
        s += __shfl_xor(s, 8, 64);
        if (mrow == 0)
            out[row0 + quad * 4 + r] = fast_sigmoid(s + b2f);
    }
}

// ---- fallback (barrier version) if workspace too small ----
__global__ void dkvmn_main(const int* __restrict__ qd, const int* __restrict__ qad,
                           const float* __restrict__ Wtab, const float* __restrict__ Q1tab,
                           const u32* __restrict__ EA,
                           const float* __restrict__ ivm,
                           const float* __restrict__ w1,
                           const float* __restrict__ w2,
                           const float* __restrict__ b2,
                           float* __restrict__ out) {
    const int tid  = threadIdx.x;
    const int b    = blockIdx.x;
    const int v    = tid;
    const int lane = tid & 63;
    const int wv   = tid >> 6;

    __shared__ alignas(16) float read_lds[4 * 52];
    __shared__ alignas(16) float part_lds[4 * 52];

    float mv[MEMN];
    if (v < VD) {
        #pragma unroll
        for (int m = 0; m < MEMN; ++m) mv[m] = ivm[m * VD + v];
    }
    float w1r[50];
    if (lane < FC) {
        #pragma unroll
        for (int i = 0; i < 50; ++i) w1r[i] = w1[(wv * 50 + i) * FC + lane];
    } else {
        #pragma unroll
        for (int i = 0; i < 50; ++i) w1r[i] = 0.f;
    }
    const float w2f = (tid < FC) ? w2[tid] : 0.f;
    const float b2f = b2[0];

    const int* qrow_i  = qd  + b * SS;
    const int* qarow_i = qad + b * SS;
    const int jchunk = v / 50;
    const int wslot  = jchunk * 52 + (v - jchunk * 50);

    for (int t = 0; t < SS; ++t) {
        const int q  = __builtin_amdgcn_readfirstlane(qrow_i[t]);
        const int qa = __builtin_amdgcn_readfirstlane(qarow_i[t]);
        const float* wrow = Wtab + q * MEMN;

        u32 ea = 0;
        if (v < VD) ea = EA[(size_t)qa * VD + v];
        float ev = bfu16_to_f((u16)(ea & 0xffffu));
        float av = bfu16_to_f((u16)(ea >> 16));

        if (v < VD) {
            float rd0 = 0.f, rd1 = 0.f;
            #pragma unroll
            for (int m = 0; m < MEMN; m += 2) {
                float wm0 = wrow[m], wm1 = wrow[m + 1];
                rd0 = fmaf(wm0, mv[m], rd0);
                mv[m] = fmaf(wm0, fmaf(-ev, mv[m], av), mv[m]);
                rd1 = fmaf(wm1, mv[m + 1], rd1);
                mv[m + 1] = fmaf(wm1, fmaf(-ev, mv[m + 1], av), mv[m + 1]);
            }
            read_lds[wslot] = rd0 + rd1;
        }
        __syncthreads();

        float part = 0.f;
        {
            const float* rlc = read_lds + wv * 52;
            #pragma unroll
            for (int i = 0; i < 48; i += 4) {
                float4 x = *(const float4*)(rlc + i);
                part = fmaf(x.x, w1r[i],     part);
                part = fmaf(x.y, w1r[i + 1], part);
                part = fmaf(x.z, w1r[i + 2], part);
                part = fmaf(x.w, w1r[i + 3], part);
            }
            part = fmaf(rlc[48], w1r[48], part);
            part = fmaf(rlc[49], w1r[49], part);
        }
        if (lane < FC) part_lds[wv * 52 + lane] = part;
        __syncthreads();

        if (wv == 0) {
            float pf = 0.f;
            if (lane < FC) {
                float h = part_lds[lane] + part_lds[52 + lane] +
                          part_lds[104 + lane] + part_lds[156 + lane] +
                          Q1tab[q * FC + lane];
                pf = fast_tanh(h) * w2f;
            }
            #pragma unroll
            for (int off = 32; off >= 1; off >>= 1) pf += __shfl_xor(pf, off, 64);
            if (lane == 0) out[b * SS + t] = fast_sigmoid(pf + b2f);
        }
    }
}

extern "C" void kernel_launch(void* const* d_in, const int* in_sizes, int n_in,
                              void* d_out, int out_size, void* d_ws, size_t ws_size,
                              hipStream_t stream) {
    const int* qd  = (const int*)d_in[0];
    const int* qad = (const int*)d_in[1];
    const float* qemb  = (const float*)d_in[2];
    const float* qaemb = (const float*)d_in[3];
    const float* km    = (const float*)d_in[4];
    const float* ivm   = (const float*)d_in[5];
    const float* ew    = (const float*)d_in[6];
    const float* eb    = (const float*)d_in[7];
    const float* aw    = (const float*)d_in[8];
    const float* ab    = (const float*)d_in[9];
    const float* w1    = (const float*)d_in[10];
    const float* b1    = (const float*)d_in[11];
    const float* w2    = (const float*)d_in[12];
    const float* b2    = (const float*)d_in[13];
    float* out = (float*)d_out;
    (void)in_sizes; (void)n_in; (void)out_size;

    char* ws = (char*)d_ws;
    float* Wt  = (float*)(ws);                       // 1,000,200 -> pad 1,000,448
    float* Q1  = (float*)(ws + 1000448);             // 1,000,200 -> pad 1,000,448
    u32*   EA  = (u32*)  (ws + 2000896);             // 8,000,800 -> pad 8,001,024
    u16*   W1s = (u16*)  (ws + 10001920);            // 28,672    -> pad 32,768
    u16*   RD  = (u16*)  (ws + 10034688);            // 163,840,000 (+512 slack)
    const size_t need = 10034688ull + 163840000ull + 512ull;

    hipMemsetAsync(out + (size_t)BB * SS, 0, (size_t)3 * BB * SS * sizeof(float), stream);

    build_wq<<<NQ1, 64, 0, stream>>>(qemb, km, w1, b1, Wt, Q1);
    build_ea<<<(NQA + EA_R - 1) / EA_R, 256, 0, stream>>>(qaemb, ew, eb, aw, ab, EA);

    if (ws_size >= need) {
        pack_w1<<<1, 256, 0, stream>>>(w1, W1s);
        dkvmn_state<<<BB, 256, 0, stream>>>(qd, qad, Wt, EA, ivm, RD);
        mlp_pred<<<(BB * SS) / 64, 256, 0, stream>>>(RD, qd, Q1, W1s, w2, b2, out);
    } else {
        dkvmn_main<<<BB, 256, 0, stream>>>(qd, qad, Wt, Q1, EA, ivm, w1, w2, b2, out);
    }
}